// Round 11
// baseline (437.756 us; speedup 1.0000x reference)
//
#include <hip/hip_runtime.h>

namespace {

constexpr int FEAT   = 128;
constexpr int NRBF   = 20;
constexpr int EPB    = 32;        // edges per block
constexpr int NNODES = 25000;
constexpr int NEDGES = 400000;
constexpr int NBLK   = NEDGES / EPB;        // 12500
constexpr int NPBLK  = (NNODES + 31) / 32;  // 782
constexpr float PI_F = 3.14159265358979323846f;

using f32x4 = __attribute__((ext_vector_type(4))) float;
using s16x8 = __attribute__((ext_vector_type(8))) short;
using s16x4 = __attribute__((ext_vector_type(4))) short;

// packed-weight layout (bf16 elements)
constexpr int PW1_ELEMS = 8  * 4 * 64 * 8;   // 16384
constexpr int PW2_ELEMS = 24 * 4 * 64 * 8;   // 49152
constexpr int PWD_ELEMS = 24 * 1 * 64 * 8;   // 12288
constexpr int PW1_OFF = 0;
constexpr int PW2_OFF = PW1_ELEMS;
constexpr int PWD_OFF = PW1_ELEMS + PW2_ELEMS;
constexpr int PT_TOTAL = PW1_ELEMS + PW2_ELEMS + PWD_ELEMS;  // 77824
constexpr int PREP_BLKS = (PT_TOTAL + 255) / 256;            // 304
constexpr int HIST_BLKS = (NEDGES + 255) / 256;              // 1563

__device__ inline unsigned short f2bf(float f) {
    unsigned u = __builtin_bit_cast(unsigned, f);
    u += 0x7fffu + ((u >> 16) & 1u);
    return (unsigned short)(u >> 16);
}
__device__ inline float bf2f(unsigned short h) {
    unsigned u = ((unsigned)h) << 16;
    return __builtin_bit_cast(float, u);
}

// ---- k1: prep (pack weights) + hist, fused (independent work) ----
// W2/Wd columns PERMUTED into 3 planes: packed col n: plane c=n>>7, f=n&127,
// original col = 3*f + c.
__global__ __launch_bounds__(256) void k1_prep_hist(
    const float* __restrict__ W1, const float* __restrict__ W2,
    const float* __restrict__ Wd, short* __restrict__ pw,
    const int* __restrict__ nbrs, int* __restrict__ hist)
{
    if (blockIdx.x < PREP_BLKS) {
        const int idx = blockIdx.x * 256 + threadIdx.x;
        if (idx >= PT_TOTAL) return;
        float val;
        if (idx < PW2_OFF) {
            const int t = idx;
            const int r = t & 7, lane = (t >> 3) & 63, ks = (t >> 9) & 3, nt = t >> 11;
            const int k = ks*32 + (lane>>4)*8 + r, n = nt*16 + (lane & 15);
            val = W1[k*128 + n];
        } else if (idx < PWD_OFF) {
            const int t = idx - PW2_OFF;
            const int r = t & 7, lane = (t >> 3) & 63, ks = (t >> 9) & 3, nt = t >> 11;
            const int k = ks*32 + (lane>>4)*8 + r, n = nt*16 + (lane & 15);
            const int orig = 3*(n & 127) + (n >> 7);
            val = W2[k*384 + orig];
        } else {
            const int t = idx - PWD_OFF;
            const int r = t & 7, lane = (t >> 3) & 63, nt = t >> 9;
            const int k = (lane>>4)*8 + r, n = nt*16 + (lane & 15);
            const int orig = 3*(n & 127) + (n >> 7);
            val = (k < NRBF) ? Wd[k*384 + orig] : 0.f;
        }
        pw[idx] = (short)f2bf(val);
    } else {
        const int e = (blockIdx.x - PREP_BLKS) * 256 + threadIdx.x;
        if (e >= NEDGES) return;
        const int2 nb = reinterpret_cast<const int2*>(nbrs)[e];
        atomicAdd(&hist[nb.x], 1);
    }
}

// ---- k2: nodephi GEMM (782 blocks) + full single-block scan (1 block) ----
__global__ __launch_bounds__(256) void k2_nodephi_scan(
    const float* __restrict__ s_j, const float* __restrict__ b1,
    const float* __restrict__ b2, const short* __restrict__ pw,
    unsigned short* __restrict__ phiT,
    const int* __restrict__ hist, int* __restrict__ cursor)
{
    if (blockIdx.x == NPBLK) {
        // ---- full exclusive scan of hist[0..NNODES) in one block ----
        __shared__ int part[256];
        const int t = threadIdx.x;
        constexpr int CH = (NNODES + 255) / 256;   // 98
        const int base = t * CH;
        int s = 0;
        for (int i = 0; i < CH; ++i) {
            const int idx = base + i;
            if (idx < NNODES) s += hist[idx];
        }
        part[t] = s;
        __syncthreads();
        for (int off = 1; off < 256; off <<= 1) {
            int v = part[t];
            if (t >= off) v += part[t - off];
            __syncthreads();
            part[t] = v;
            __syncthreads();
        }
        int run = part[t] - s;        // exclusive prefix of this chunk
        for (int i = 0; i < CH; ++i) {
            const int idx = base + i;
            if (idx < NNODES) { cursor[idx] = run; run += hist[idx]; }
        }
        return;
    }

    // ---- nodephi GEMM ----
    __shared__ short sT[8192];           // sA [0,4096), sH [4096,8192)
    constexpr int OFF_H = 4096;
    const int tid = threadIdx.x;
    const int w   = tid >> 6;
    const int l   = tid & 63;
    const int mr  = l & 15;
    const int g   = l >> 4;
    const int n0  = blockIdx.x * 32;

    // P0: coalesced load of 32 node rows -> bf16 LDS (zero-pad past NNODES)
    #pragma unroll
    for (int p = 0; p < 4; ++p) {
        const int v  = tid + p*256;
        const int e  = v >> 5;
        const int c4 = (v & 31) * 4;
        const int node = n0 + e;
        float4 f = {0.f, 0.f, 0.f, 0.f};
        if (node < NNODES)
            f = reinterpret_cast<const float4*>(s_j + (size_t)node*FEAT)[v & 31];
        s16x4 h;
        h.x = (short)f2bf(f.x); h.y = (short)f2bf(f.y);
        h.z = (short)f2bf(f.z); h.w = (short)f2bf(f.w);
        *reinterpret_cast<s16x4*>(&sT[e*128 + (c4 ^ ((e & 7) << 3))]) = h;
    }
    __syncthreads();

    // P1: h = swish(s@W1+b1)
    {
        s16x8 aS[2][4];
        #pragma unroll
        for (int mt = 0; mt < 2; ++mt) {
            const int m = mt*16 + mr;
            const int xr = (m & 7) << 3;
            #pragma unroll
            for (int ks = 0; ks < 4; ++ks)
                aS[mt][ks] = *reinterpret_cast<const s16x8*>(&sT[m*128 + ((ks*32 + g*8) ^ xr)]);
        }
        const s16x8* pW1 = reinterpret_cast<const s16x8*>(pw + PW1_OFF);
        #pragma unroll
        for (int i = 0; i < 2; ++i) {
            const int nt = w*2 + i;
            const int n  = nt*16 + mr;
            const float b1n = b1[n];
            f32x4 acc[2] = {f32x4{0,0,0,0}, f32x4{0,0,0,0}};
            #pragma unroll
            for (int ks = 0; ks < 4; ++ks) {
                const s16x8 b = pW1[(nt*4 + ks)*64 + l];
                acc[0] = __builtin_amdgcn_mfma_f32_16x16x32_bf16(aS[0][ks], b, acc[0], 0, 0, 0);
                acc[1] = __builtin_amdgcn_mfma_f32_16x16x32_bf16(aS[1][ks], b, acc[1], 0, 0, 0);
            }
            #pragma unroll
            for (int mt = 0; mt < 2; ++mt)
                #pragma unroll
                for (int r = 0; r < 4; ++r) {
                    const int m = mt*16 + g*4 + r;
                    const float x = acc[mt][r] + b1n;
                    const float hsw = x / (1.0f + __expf(-x));
                    sT[OFF_H + m*128 + (n ^ ((m & 7) << 3))] = (short)f2bf(hsw);
                }
        }
    }
    __syncthreads();

    // P2: phi = h@W2+b2 -> global phi planes (bf16)
    {
        s16x8 aH[2][4];
        #pragma unroll
        for (int mt = 0; mt < 2; ++mt) {
            const int m = mt*16 + mr;
            const int xr = (m & 7) << 3;
            #pragma unroll
            for (int ks = 0; ks < 4; ++ks)
                aH[mt][ks] = *reinterpret_cast<const s16x8*>(&sT[OFF_H + m*128 + ((ks*32 + g*8) ^ xr)]);
        }
        const s16x8* pW2 = reinterpret_cast<const s16x8*>(pw + PW2_OFF);
        #pragma unroll
        for (int i = 0; i < 6; ++i) {
            const int nt = w*6 + i;
            const int n  = nt*16 + mr;            // packed col
            const int c  = n >> 7;
            const int f2 = n & 127;
            const float b2n = b2[3*f2 + c];
            f32x4 acc[2] = {f32x4{0,0,0,0}, f32x4{0,0,0,0}};
            #pragma unroll
            for (int ks = 0; ks < 4; ++ks) {
                const s16x8 b = pW2[(nt*4 + ks)*64 + l];
                acc[0] = __builtin_amdgcn_mfma_f32_16x16x32_bf16(aH[0][ks], b, acc[0], 0, 0, 0);
                acc[1] = __builtin_amdgcn_mfma_f32_16x16x32_bf16(aH[1][ks], b, acc[1], 0, 0, 0);
            }
            #pragma unroll
            for (int mt = 0; mt < 2; ++mt)
                #pragma unroll
                for (int r = 0; r < 4; ++r) {
                    const int m = mt*16 + g*4 + r;
                    const int node = n0 + m;
                    if (node < NNODES)
                        phiT[(size_t)c*NNODES*FEAT + (size_t)node*FEAT + f2] =
                            f2bf(acc[mt][r] + b2n);
                }
        }
    }
}

// ---- scatter: emit packed edge records sorted by dst ----
__global__ __launch_bounds__(256) void scatter_kernel(
    const int* __restrict__ nbrs, const float* __restrict__ r_ij,
    int* __restrict__ cursor, int2* __restrict__ recDS, float4* __restrict__ recR)
{
    const int e = blockIdx.x * 256 + threadIdx.x;
    if (e >= NEDGES) return;
    const int2 nb = reinterpret_cast<const int2*>(nbrs)[e];
    const int pos = atomicAdd(&cursor[nb.x], 1);
    recDS[pos] = nb;
    recR[pos] = make_float4(r_ij[3*e+0], r_ij[3*e+1], r_ij[3*e+2], 0.f);
}

// ---- edge kernel (records pre-sorted by dst) ----
// LDS: inv/phi planes [0,12288) shorts, sR [12288,14336)
__global__ __launch_bounds__(256) void msg_kernel(
    const float* __restrict__ v_j, const int2* __restrict__ recDS,
    const float4* __restrict__ recR, const float* __restrict__ bd,
    const short* __restrict__ pw, const unsigned short* __restrict__ phiT,
    float* __restrict__ ds_out, float* __restrict__ dv_out)
{
    __shared__ short sP[14336];          // 28 KB
    __shared__ float sU[EPB][3];
    __shared__ int   sSrc[EPB], sDst[EPB];
    constexpr int OFF_R = 12288;

    const int tid = threadIdx.x;
    const int w   = tid >> 6;
    const int l   = tid & 63;
    const int mr  = l & 15;
    const int g   = l >> 4;
    const int e0  = blockIdx.x * EPB;

    // P0a: per-edge meta, 8 threads per edge (coalesced record reads)
    {
        const int ep  = tid >> 3;
        const int sub = tid & 7;
        const int2  nb = recDS[e0 + ep];
        const float4 r = recR[e0 + ep];
        const float d     = sqrtf(r.x*r.x + r.y*r.y + r.z*r.z + 3e-15f);
        const float inv_d = 1.0f / d;
        if (sub == 0) {
            sDst[ep] = nb.x; sSrc[ep] = nb.y;
            sU[ep][0] = r.x*inv_d; sU[ep][1] = r.y*inv_d; sU[ep][2] = r.z*inv_d;
        }
        s16x8 rv;
        #pragma unroll
        for (int kk = 0; kk < 8; ++kk) {
            const int k = sub*8 + kk;
            const float v = (k < NRBF) ? __sinf((float)(k+1)*(PI_F/5.0f)*d)*inv_d : 0.f;
            rv[kk] = (short)f2bf(v);
        }
        *reinterpret_cast<s16x8*>(&sP[OFF_R + ep*64 + ((sub*8) ^ ((ep & 7) << 3))]) = rv;
    }

    // P0b: gather phi plane rows (bf16, 16B chunks) -> LDS planes
    #pragma unroll
    for (int pl = 0; pl < 3; ++pl) {
        #pragma unroll
        for (int p = 0; p < 2; ++p) {
            const int v  = tid + p*256;        // 0..511
            const int e  = v >> 4;
            const int ch = (v & 15) * 8;       // bf16 elem offset in row
            const int src = recDS[e0 + e].y;
            const s16x8 val = *reinterpret_cast<const s16x8*>(
                phiT + (size_t)pl*NNODES*FEAT + (size_t)src*FEAT + ch);
            *reinterpret_cast<s16x8*>(&sP[pl*4096 + e*128 + (ch ^ ((e & 7) << 3))]) = val;
        }
    }
    __syncthreads();

    // P2: ws = rbf@Wd+bd (MFMA); inv = phi*ws in-place in LDS planes
    {
        s16x8 aR[2];
        #pragma unroll
        for (int mt = 0; mt < 2; ++mt) {
            const int m = mt*16 + mr;
            aR[mt] = *reinterpret_cast<const s16x8*>(&sP[OFF_R + m*64 + ((g*8) ^ ((m & 7) << 3))]);
        }
        const s16x8* pWd = reinterpret_cast<const s16x8*>(pw + PWD_OFF);
        #pragma unroll
        for (int i = 0; i < 6; ++i) {
            const int nt = w*6 + i;
            const int n  = nt*16 + mr;            // packed col
            const int c  = n >> 7;
            const int f2 = n & 127;
            const float bdn = bd[3*f2 + c];
            const s16x8 bw = pWd[nt*64 + l];
            f32x4 accw[2] = {f32x4{0,0,0,0}, f32x4{0,0,0,0}};
            accw[0] = __builtin_amdgcn_mfma_f32_16x16x32_bf16(aR[0], bw, accw[0], 0, 0, 0);
            accw[1] = __builtin_amdgcn_mfma_f32_16x16x32_bf16(aR[1], bw, accw[1], 0, 0, 0);
            #pragma unroll
            for (int mt = 0; mt < 2; ++mt)
                #pragma unroll
                for (int r = 0; r < 4; ++r) {
                    const int m = mt*16 + g*4 + r;
                    const int addr = c*4096 + m*128 + (f2 ^ ((m & 7) << 3));
                    const float phi = bf2f((unsigned short)sP[addr]);
                    sP[addr] = (short)f2bf(phi * (accw[mt][r] + bdn));
                }
        }
    }
    __syncthreads();

    // P3: segmented scatter-add, vj preloaded per 8-edge chunk for MLP
    {
        const int half = tid >> 7;
        const int f    = tid & 127;
        const int eb   = half * 16;
        float accS = 0.f, a0 = 0.f, a1 = 0.f, a2 = 0.f;
        int cur = sDst[eb];
        #pragma unroll
        for (int chunk = 0; chunk < 2; ++chunk) {
            float vx[8], vy[8], vz[8];
            #pragma unroll
            for (int j = 0; j < 8; ++j) {
                const int e = eb + chunk*8 + j;
                const float* vj = v_j + (size_t)sSrc[e]*(3*FEAT) + 3*f;
                vx[j] = vj[0]; vy[j] = vj[1]; vz[j] = vj[2];
            }
            #pragma unroll
            for (int j = 0; j < 8; ++j) {
                const int e = eb + chunk*8 + j;
                const int d = sDst[e];
                if (d != cur) {
                    atomicAdd(ds_out + (size_t)cur*FEAT + f, accS);
                    float* dvp = dv_out + (size_t)cur*(3*FEAT) + 3*f;
                    atomicAdd(dvp + 0, a0);
                    atomicAdd(dvp + 1, a1);
                    atomicAdd(dvp + 2, a2);
                    accS = a0 = a1 = a2 = 0.f;
                    cur = d;
                }
                const int fx = f ^ ((e & 7) << 3);
                const float i0 = bf2f((unsigned short)sP[        e*128 + fx]);
                const float i1 = bf2f((unsigned short)sP[4096 + e*128 + fx]);
                const float i2 = bf2f((unsigned short)sP[8192 + e*128 + fx]);
                const float u0 = sU[e][0], u1 = sU[e][1], u2 = sU[e][2];
                accS += i1;
                a0 += i2*u0 + i0*vx[j];
                a1 += i2*u1 + i0*vy[j];
                a2 += i2*u2 + i0*vz[j];
            }
        }
        atomicAdd(ds_out + (size_t)cur*FEAT + f, accS);
        float* dvp = dv_out + (size_t)cur*(3*FEAT) + 3*f;
        atomicAdd(dvp + 0, a0);
        atomicAdd(dvp + 1, a1);
        atomicAdd(dvp + 2, a2);
    }
}

} // anonymous namespace

extern "C" void kernel_launch(void* const* d_in, const int* in_sizes, int n_in,
                              void* d_out, int out_size, void* d_ws, size_t ws_size,
                              hipStream_t stream)
{
    const float* s_j  = (const float*)d_in[0];
    const float* v_j  = (const float*)d_in[1];
    const float* r_ij = (const float*)d_in[2];
    const int*   nbrs = (const int*)d_in[3];
    const float* W1   = (const float*)d_in[4];
    const float* b1   = (const float*)d_in[5];
    const float* W2   = (const float*)d_in[6];
    const float* b2   = (const float*)d_in[7];
    const float* Wd   = (const float*)d_in[8];
    const float* bd   = (const float*)d_in[9];

    float* ds_out = (float*)d_out;
    float* dv_out = ds_out + (size_t)NNODES * FEAT;

    char* base = (char*)d_ws;
    short* pw            = (short*)base;                         // 155,648 B
    int*   hist          = (int*)(base + 160*1024);              // 100,000 B
    int*   cursor        = (int*)(base + 272*1024);              // 100,000 B
    int2*  recDS         = (int2*)(base + 512*1024);             // 3.2 MB
    float4* recR         = (float4*)(base + 4ull*1024*1024);     // 6.4 MB
    unsigned short* phiT = (unsigned short*)(base + 16ull*1024*1024); // 19.2 MB

    hipMemsetAsync(d_out, 0, (size_t)out_size * sizeof(float), stream);
    hipMemsetAsync(hist, 0, NNODES * sizeof(int), stream);

    k1_prep_hist<<<PREP_BLKS + HIST_BLKS, 256, 0, stream>>>(
        W1, W2, Wd, pw, nbrs, hist);
    k2_nodephi_scan<<<NPBLK + 1, 256, 0, stream>>>(
        s_j, b1, b2, pw, phiT, hist, cursor);
    scatter_kernel<<<(NEDGES + 255)/256, 256, 0, stream>>>(
        nbrs, r_ij, cursor, recDS, recR);

    msg_kernel<<<NBLK, 256, 0, stream>>>(
        v_j, recDS, recR, bd, pw, phiT, ds_out, dv_out);
}